// Round 1
// baseline (151.110 us; speedup 1.0000x reference)
//
#include <hip/hip_runtime.h>
#include <hip/hip_bf16.h>

#define B_ 2
#define H_ 16
#define S_ 2048
#define D_ 64
#define BQ 64
#define BK 64
#define LDSTR 72   // 64 + 8 pad: 2-way LDS bank aliasing only (free), keeps 16B alignment

typedef _Float16 half8 __attribute__((ext_vector_type(8)));
typedef float floatx4 __attribute__((ext_vector_type(4)));

__global__ __launch_bounds__(256, 2)
void t5_attn_kernel(const float* __restrict__ qg_, const float* __restrict__ kg_,
                    const float* __restrict__ vg_, const float* __restrict__ bt,
                    const int* __restrict__ elen, float* __restrict__ outg_)
{
    __shared__ __align__(16) _Float16 Kl[BK][LDSTR];     // [key][dim]
    __shared__ __align__(16) _Float16 Vt[D_][LDSTR];     // [dim][key] (transposed)
    __shared__ __align__(16) _Float16 Pl[4][16][LDSTR];  // per-wave P tile [qrow][key]
    __shared__ float lut[256];                           // bias by clamped distance

    const int qblk = blockIdx.x;
    const int h    = blockIdx.y;
    const int b    = blockIdx.z;
    const int tid  = threadIdx.x;
    const int wave = tid >> 6;
    const int lane = tid & 63;
    const int quad = lane >> 4;
    const int t16  = lane & 15;

    // ---- bias LUT: lut[n] = bias_table[bucket(n)][h], n = clamp(i-j,0,255)
    {
        int n = tid;  // 256 threads, 256 entries
        int bucket;
        if (n < 16) {
            bucket = n;
        } else {
            int vl = (int)(__log2f((float)n * 0.0625f) * 4.0f);
            bucket = 16 + (vl < 15 ? vl : 15);
        }
        lut[n] = bt[bucket * H_ + h];
    }

    // robust event_length read: works whether harness stored int32 or int64.
    // int32 case: el = [len0, len1], el[1] = len1 >= 1 (nonzero).
    // int64 case: el = [len0_lo, 0, len1_lo, 0], el[1] == 0.
    const int len = (elen[1] == 0) ? elen[2 * b] : elen[b];
    const int ntiles = (len + BK - 1) >> 6;  // keys beyond len contribute exp()=0 exactly

    const size_t bh = ((size_t)b * H_ + h) * (size_t)(S_ * D_);
    const float* qg = qg_ + bh;
    const float* kg = kg_ + bh;
    const float* vg = vg_ + bh;
    float*       og = outg_ + bh;

    // ---- Q fragments (A-layout: A[m=t16][k=quad*8+j]), scaled by 1/sqrt(D)=0.125
    half8 qf[2];
    {
        const int row = qblk * BQ + wave * 16 + t16;
        const float* qp = qg + (size_t)row * D_ + quad * 8;
        #pragma unroll
        for (int c = 0; c < 2; ++c) {
            const float4* p = reinterpret_cast<const float4*>(qp + c * 32);
            float4 x0 = p[0], x1 = p[1];
            half8 hv;
            hv[0] = (_Float16)(x0.x * 0.125f); hv[1] = (_Float16)(x0.y * 0.125f);
            hv[2] = (_Float16)(x0.z * 0.125f); hv[3] = (_Float16)(x0.w * 0.125f);
            hv[4] = (_Float16)(x1.x * 0.125f); hv[5] = (_Float16)(x1.y * 0.125f);
            hv[6] = (_Float16)(x1.z * 0.125f); hv[7] = (_Float16)(x1.w * 0.125f);
            qf[c] = hv;
        }
    }

    floatx4 zero4 = {0.f, 0.f, 0.f, 0.f};
    floatx4 acc[4];            // O accumulator: acc[nb][r] -> row quad*4+r, dim nb*16+t16
    float m_[4], l_[4];        // online-softmax state per row (replicated across t16 lanes)
    #pragma unroll
    for (int nb = 0; nb < 4; ++nb) acc[nb] = zero4;
    #pragma unroll
    for (int r = 0; r < 4; ++r) { m_[r] = -INFINITY; l_[r] = 0.f; }

    const int i0 = qblk * BQ + wave * 16 + quad * 4;  // global q-row of reg r=0

    for (int kt = 0; kt < ntiles; ++kt) {
        __syncthreads();  // previous iteration's LDS reads complete before restage

        // ---- stage K tile [key][dim] (coalesced 32B/thread reads, b128 LDS writes)
        #pragma unroll
        for (int it = 0; it < 2; ++it) {
            int idx = tid + it * 256;
            int row = idx >> 3;
            int c8  = (idx & 7) << 3;
            const float4* p = reinterpret_cast<const float4*>(
                kg + ((size_t)(kt * BK + row) * D_ + c8));
            float4 x0 = p[0], x1 = p[1];
            half8 hv;
            hv[0]=(_Float16)x0.x; hv[1]=(_Float16)x0.y; hv[2]=(_Float16)x0.z; hv[3]=(_Float16)x0.w;
            hv[4]=(_Float16)x1.x; hv[5]=(_Float16)x1.y; hv[6]=(_Float16)x1.z; hv[7]=(_Float16)x1.w;
            *reinterpret_cast<half8*>(&Kl[row][c8]) = hv;
        }
        // ---- stage V transposed [dim][key]: lane=dim, each of 8 reads is a full
        // coalesced 256B row of V; write 8 consecutive keys as one b128.
        #pragma unroll
        for (int it = 0; it < 2; ++it) {
            int key8 = wave * 8 + it * 32;
            half8 hv;
            #pragma unroll
            for (int jj = 0; jj < 8; ++jj)
                hv[jj] = (_Float16)vg[(size_t)(kt * BK + key8 + jj) * D_ + lane];
            *reinterpret_cast<half8*>(&Vt[lane][key8]) = hv;
        }
        __syncthreads();

        // ---- S = (Q/8) K^T : 2 k-chunks x 4 key-blocks of 16x16x32 MFMA
        floatx4 sa[4];
        #pragma unroll
        for (int nb = 0; nb < 4; ++nb) sa[nb] = zero4;
        #pragma unroll
        for (int kc = 0; kc < 2; ++kc) {
            half8 a = qf[kc];
            #pragma unroll
            for (int nb = 0; nb < 4; ++nb) {
                half8 bb = *reinterpret_cast<const half8*>(
                    &Kl[nb * 16 + t16][kc * 32 + quad * 8]);
                sa[nb] = __builtin_amdgcn_mfma_f32_16x16x32_f16(a, bb, sa[nb], 0, 0, 0);
            }
        }

        // ---- bias + key mask (C-layout: row=quad*4+r, col=nb*16+t16)
        #pragma unroll
        for (int nb = 0; nb < 4; ++nb) {
            int j = kt * BK + nb * 16 + t16;
            bool valid = j < len;
            #pragma unroll
            for (int r = 0; r < 4; ++r) {
                int d = i0 + r - j;
                d = d < 0 ? 0 : (d > 255 ? 255 : d);
                float sv = sa[nb][r] + lut[d];
                sa[nb][r] = valid ? sv : -1e30f;  // exp() underflows to exactly 0
            }
        }

        // ---- online softmax per row
        float pv[4][4];
        #pragma unroll
        for (int r = 0; r < 4; ++r) {
            float rmax = fmaxf(fmaxf(sa[0][r], sa[1][r]), fmaxf(sa[2][r], sa[3][r]));
            #pragma unroll
            for (int off = 1; off < 16; off <<= 1)
                rmax = fmaxf(rmax, __shfl_xor(rmax, off, 64));
            float mnew  = fmaxf(m_[r], rmax);
            float alpha = __expf(m_[r] - mnew);   // first tile: exp(-inf)=0
            m_[r] = mnew;
            float rsum = 0.f;
            #pragma unroll
            for (int nb = 0; nb < 4; ++nb) {
                float p = __expf(sa[nb][r] - mnew);
                pv[nb][r] = p;
                rsum += p;
            }
            #pragma unroll
            for (int off = 1; off < 16; off <<= 1)
                rsum += __shfl_xor(rsum, off, 64);
            l_[r] = l_[r] * alpha + rsum;
            #pragma unroll
            for (int nb = 0; nb < 4; ++nb) acc[nb][r] *= alpha;
        }

        // ---- P: C-layout -> LDS -> A-layout (verified flash transform)
        #pragma unroll
        for (int r = 0; r < 4; ++r) {
            #pragma unroll
            for (int nb = 0; nb < 4; ++nb)
                Pl[wave][quad * 4 + r][nb * 16 + t16] = (_Float16)pv[nb][r];
        }
        __syncthreads();  // conservative: guarantees P visible before A-frag reads

        // ---- O += P V : A from Pl rows (b128), B from Vt rows (b128)
        #pragma unroll
        for (int kc = 0; kc < 2; ++kc) {
            half8 a = *reinterpret_cast<const half8*>(
                &Pl[wave][t16][kc * 32 + quad * 8]);
            #pragma unroll
            for (int nb = 0; nb < 4; ++nb) {
                half8 bb = *reinterpret_cast<const half8*>(
                    &Vt[nb * 16 + t16][kc * 32 + quad * 8]);
                acc[nb] = __builtin_amdgcn_mfma_f32_16x16x32_f16(a, bb, acc[nb], 0, 0, 0);
            }
        }
    }

    // ---- epilogue: normalize and store (fp32 out)
    #pragma unroll
    for (int r = 0; r < 4; ++r) {
        float inv = 1.f / l_[r];
        #pragma unroll
        for (int nb = 0; nb < 4; ++nb) {
            og[(size_t)(qblk * BQ + wave * 16 + quad * 4 + r) * D_ + nb * 16 + t16]
                = acc[nb][r] * inv;
        }
    }
}

extern "C" void kernel_launch(void* const* d_in, const int* in_sizes, int n_in,
                              void* d_out, int out_size, void* d_ws, size_t ws_size,
                              hipStream_t stream) {
    const float* q  = (const float*)d_in[0];
    const float* k  = (const float*)d_in[1];
    const float* v  = (const float*)d_in[2];
    const float* bt = (const float*)d_in[3];
    const int*   el = (const int*)d_in[4];
    float* out = (float*)d_out;
    dim3 grid(S_ / BQ, H_, B_);  // 32 q-blocks fastest -> consecutive blocks share K/V in L2
    t5_attn_kernel<<<grid, 256, 0, stream>>>(q, k, v, bt, el, out);
}

// Round 2
// 148.051 us; speedup vs baseline: 1.0207x; 1.0207x over previous
//
#include <hip/hip_runtime.h>
#include <hip/hip_bf16.h>

#define B_ 2
#define H_ 16
#define S_ 2048
#define D_ 64
#define BQ 64
#define BK 64
#define LDSTR 72   // stride 144B = 9 x 16B bank-quads -> conflict-free b128 access
#define LOG2E 1.4426950408889634f

#if __has_builtin(__builtin_amdgcn_exp2f)
#define EXP2F(x) __builtin_amdgcn_exp2f(x)
#else
#define EXP2F(x) __expf((x) * 0.6931471805599453f)
#endif

typedef _Float16 half8 __attribute__((ext_vector_type(8)));
typedef float floatx4 __attribute__((ext_vector_type(4)));

__global__ __launch_bounds__(256, 3)
void t5_attn_kernel(const float* __restrict__ qg_, const float* __restrict__ kg_,
                    const float* __restrict__ vg_, const float* __restrict__ bt,
                    const int* __restrict__ elen, float* __restrict__ outg_)
{
    __shared__ __align__(16) _Float16 Kl[BK][LDSTR];     // [key][dim]
    __shared__ __align__(16) _Float16 Vt[D_][LDSTR];     // [dim][key] (transposed)
    __shared__ __align__(16) _Float16 Pl[4][16][LDSTR];  // per-wave P tile [qrow][key]
    __shared__ float lut[256];                           // log2e * bias by clamped distance

    const int qblk = blockIdx.x;
    const int h    = blockIdx.y;
    const int b    = blockIdx.z;
    const int tid  = threadIdx.x;
    const int wave = tid >> 6;
    const int lane = tid & 63;
    const int quad = lane >> 4;
    const int t16  = lane & 15;

    // ---- bias LUT (pre-scaled by log2e): lut[n] = bt[bucket(n)][h] * log2e
    {
        int n = tid;
        int bucket;
        if (n < 16) {
            bucket = n;
        } else {
            int vl = (int)(__log2f((float)n * 0.0625f) * 4.0f);
            bucket = 16 + (vl < 15 ? vl : 15);
        }
        lut[n] = bt[bucket * H_ + h] * LOG2E;
    }
    // tile-uniform bias constants (all-future: bucket 0; far-past d>=216: bucket 31)
    const float c_next = bt[h] * LOG2E;
    const float c_far  = bt[31 * H_ + h] * LOG2E;

    // robust event_length read (int32 vs int64 layouts; valid lengths >= 1)
    const int len = (elen[1] == 0) ? elen[2 * b] : elen[b];
    const int ntiles = (len + BK - 1) >> 6;  // keys beyond len contribute exp()=0 exactly

    const size_t bh = ((size_t)b * H_ + h) * (size_t)(S_ * D_);
    const float* qg = qg_ + bh;
    const float* kg = kg_ + bh;
    const float* vg = vg_ + bh;
    float*       og = outg_ + bh;

    // ---- Q fragments (A-layout), scaled by (1/sqrt(64)) * log2e
    half8 qf[2];
    {
        const float qscale = 0.125f * LOG2E;
        const int row = qblk * BQ + wave * 16 + t16;
        const float* qp = qg + (size_t)row * D_ + quad * 8;
        #pragma unroll
        for (int c = 0; c < 2; ++c) {
            const float4* p = reinterpret_cast<const float4*>(qp + c * 32);
            float4 x0 = p[0], x1 = p[1];
            half8 hv;
            hv[0] = (_Float16)(x0.x * qscale); hv[1] = (_Float16)(x0.y * qscale);
            hv[2] = (_Float16)(x0.z * qscale); hv[3] = (_Float16)(x0.w * qscale);
            hv[4] = (_Float16)(x1.x * qscale); hv[5] = (_Float16)(x1.y * qscale);
            hv[6] = (_Float16)(x1.z * qscale); hv[7] = (_Float16)(x1.w * qscale);
            qf[c] = hv;
        }
    }

    floatx4 zero4 = {0.f, 0.f, 0.f, 0.f};
    floatx4 acc[4];            // O accumulator: acc[nb][r] -> row quad*4+r, dim nb*16+t16
    float m_[4], l_[4];        // online-softmax state (log2 domain), replicated across t16
    #pragma unroll
    for (int nb = 0; nb < 4; ++nb) acc[nb] = zero4;
    #pragma unroll
    for (int r = 0; r < 4; ++r) { m_[r] = -INFINITY; l_[r] = 0.f; }

    const int i0 = qblk * BQ + wave * 16 + quad * 4;  // global q-row of reg r=0

    // ---- software-pipelined staging registers
    float4 kx[2][2];
    float  vx[16];
    auto prefetch = [&](int kt) {
        #pragma unroll
        for (int it = 0; it < 2; ++it) {
            int idx = tid + it * 256;
            int row = idx >> 3;
            int c8  = (idx & 7) << 3;
            const float4* p = reinterpret_cast<const float4*>(
                kg + ((size_t)(kt * BK + row) * D_ + c8));
            kx[it][0] = p[0];
            kx[it][1] = p[1];
        }
        #pragma unroll
        for (int it = 0; it < 2; ++it) {
            int key8 = kt * BK + wave * 8 + it * 32;
            #pragma unroll
            for (int jj = 0; jj < 8; ++jj)
                vx[it * 8 + jj] = vg[(size_t)(key8 + jj) * D_ + lane];
        }
    };

    prefetch(0);

    for (int kt = 0; kt < ntiles; ++kt) {
        __syncthreads();  // all waves done reading prior tile's LDS

        // ---- stage K [key][dim] and V^T [dim][key] from prefetched regs (cvt here)
        #pragma unroll
        for (int it = 0; it < 2; ++it) {
            int idx = tid + it * 256;
            int row = idx >> 3;
            int c8  = (idx & 7) << 3;
            float4 x0 = kx[it][0], x1 = kx[it][1];
            half8 hv;
            hv[0]=(_Float16)x0.x; hv[1]=(_Float16)x0.y; hv[2]=(_Float16)x0.z; hv[3]=(_Float16)x0.w;
            hv[4]=(_Float16)x1.x; hv[5]=(_Float16)x1.y; hv[6]=(_Float16)x1.z; hv[7]=(_Float16)x1.w;
            *reinterpret_cast<half8*>(&Kl[row][c8]) = hv;
        }
        #pragma unroll
        for (int it = 0; it < 2; ++it) {
            int key8 = wave * 8 + it * 32;
            half8 hv;
            #pragma unroll
            for (int jj = 0; jj < 8; ++jj) hv[jj] = (_Float16)vx[it * 8 + jj];
            *reinterpret_cast<half8*>(&Vt[lane][key8]) = hv;
        }
        __syncthreads();

        // issue next tile's global loads now; latency hides under compute below
        if (kt + 1 < ntiles) prefetch(kt + 1);

        // ---- S = (Q * log2e/8) K^T
        floatx4 sa[4];
        #pragma unroll
        for (int nb = 0; nb < 4; ++nb) sa[nb] = zero4;
        #pragma unroll
        for (int kc = 0; kc < 2; ++kc) {
            half8 a = qf[kc];
            #pragma unroll
            for (int nb = 0; nb < 4; ++nb) {
                half8 bb = *reinterpret_cast<const half8*>(
                    &Kl[nb * 16 + t16][kc * 32 + quad * 8]);
                sa[nb] = __builtin_amdgcn_mfma_f32_16x16x32_f16(a, bb, sa[nb], 0, 0, 0);
            }
        }

        // ---- bias: tile-uniform constant except within 5 tiles of the diagonal
        float cbias;
        bool lutmode;
        if (kt > qblk)          { cbias = c_next; lutmode = false; }
        else if (kt < qblk - 4) { cbias = c_far;  lutmode = false; }
        else                    { cbias = 0.f;    lutmode = true;  }

        if (lutmode) {
            const int d0 = i0 - kt * BK - t16;  // + r - nb*16 per element
            #pragma unroll
            for (int nb = 0; nb < 4; ++nb) {
                #pragma unroll
                for (int r = 0; r < 4; ++r) {
                    int d = d0 + r - nb * 16;
                    d = d < 0 ? 0 : (d > 255 ? 255 : d);
                    sa[nb][r] += lut[d];
                }
            }
        }
        // key-padding mask: only the (block-uniform) boundary tile needs it
        if ((kt == ntiles - 1) && (len & 63)) {
            #pragma unroll
            for (int nb = 0; nb < 4; ++nb) {
                bool valid = (kt * BK + nb * 16 + t16) < len;
                #pragma unroll
                for (int r = 0; r < 4; ++r)
                    sa[nb][r] = valid ? sa[nb][r] : -1e30f;
            }
        }

        // ---- online softmax (log2 domain); uniform bias deferred into the shift
        #pragma unroll
        for (int r = 0; r < 4; ++r) {
            float rmax = fmaxf(fmaxf(sa[0][r], sa[1][r]), fmaxf(sa[2][r], sa[3][r]));
            #pragma unroll
            for (int off = 1; off < 16; off <<= 1)
                rmax = fmaxf(rmax, __shfl_xor(rmax, off, 64));
            float mnew  = fmaxf(m_[r], rmax + cbias);
            float alpha = EXP2F(m_[r] - mnew);   // first tile: exp2(-inf)=0
            float t     = mnew - cbias;
            m_[r] = mnew;
            #pragma unroll
            for (int nb = 0; nb < 4; ++nb)
                sa[nb][r] = EXP2F(sa[nb][r] - t);
            float rsum = (sa[0][r] + sa[1][r]) + (sa[2][r] + sa[3][r]);
            #pragma unroll
            for (int off = 1; off < 16; off <<= 1)
                rsum += __shfl_xor(rsum, off, 64);
            l_[r] = l_[r] * alpha + rsum;
            #pragma unroll
            for (int nb = 0; nb < 4; ++nb) acc[nb][r] *= alpha;
        }

        // ---- P: C-layout -> per-wave LDS -> A-layout (wave-local, no block barrier)
        #pragma unroll
        for (int r = 0; r < 4; ++r) {
            #pragma unroll
            for (int nb = 0; nb < 4; ++nb)
                Pl[wave][quad * 4 + r][nb * 16 + t16] = (_Float16)sa[nb][r];
        }
        asm volatile("s_waitcnt lgkmcnt(0)" ::: "memory");  // own wave's writes visible

        // ---- O += P V
        #pragma unroll
        for (int kc = 0; kc < 2; ++kc) {
            half8 a = *reinterpret_cast<const half8*>(
                &Pl[wave][t16][kc * 32 + quad * 8]);
            #pragma unroll
            for (int nb = 0; nb < 4; ++nb) {
                half8 bb = *reinterpret_cast<const half8*>(
                    &Vt[nb * 16 + t16][kc * 32 + quad * 8]);
                acc[nb] = __builtin_amdgcn_mfma_f32_16x16x32_f16(a, bb, acc[nb], 0, 0, 0);
            }
        }
    }

    // ---- epilogue: normalize and store (fp32 out)
    #pragma unroll
    for (int r = 0; r < 4; ++r) {
        float inv = 1.f / l_[r];
        #pragma unroll
        for (int nb = 0; nb < 4; ++nb) {
            og[(size_t)(qblk * BQ + wave * 16 + quad * 4 + r) * D_ + nb * 16 + t16]
                = acc[nb][r] * inv;
        }
    }
}

extern "C" void kernel_launch(void* const* d_in, const int* in_sizes, int n_in,
                              void* d_out, int out_size, void* d_ws, size_t ws_size,
                              hipStream_t stream) {
    const float* q  = (const float*)d_in[0];
    const float* k  = (const float*)d_in[1];
    const float* v  = (const float*)d_in[2];
    const float* bt = (const float*)d_in[3];
    const int*   el = (const int*)d_in[4];
    float* out = (float*)d_out;
    dim3 grid(S_ / BQ, H_, B_);
    t5_attn_kernel<<<grid, 256, 0, stream>>>(q, k, v, bt, el, out);
}

// Round 3
// 127.449 us; speedup vs baseline: 1.1856x; 1.1616x over previous
//
#include <hip/hip_runtime.h>
#include <hip/hip_bf16.h>

#define B_ 2
#define H_ 16
#define S_ 2048
#define D_ 64
#define BQ 64
#define BK 64
#define LDSTR 72   // stride 144B: b128 accesses spread 8 lanes/bank-quad (throughput-optimal)
#define LOG2E 1.4426950408889634f
#define FIXM 10.0f // fixed softmax shift (log2 domain); exact since it cancels in O = PV/l

#if __has_builtin(__builtin_amdgcn_exp2f)
#define EXP2F(x) __builtin_amdgcn_exp2f(x)
#else
#define EXP2F(x) __expf((x) * 0.6931471805599453f)
#endif

typedef _Float16 half8 __attribute__((ext_vector_type(8)));
typedef float floatx4 __attribute__((ext_vector_type(4)));

__global__ __launch_bounds__(256, 3)
void t5_attn_kernel(const float* __restrict__ qg_, const float* __restrict__ kg_,
                    const float* __restrict__ vg_, const float* __restrict__ bt,
                    const int* __restrict__ elen, float* __restrict__ outg_)
{
    __shared__ __align__(16) _Float16 Kl[BK][LDSTR];     // [key][dim]
    __shared__ __align__(16) _Float16 Vt[D_][LDSTR];     // [dim][key] (transposed)
    __shared__ __align__(16) _Float16 Pl[4][16][LDSTR];  // per-wave P tile [qrow][key]
    __shared__ float lut[256];                           // bias*log2e - FIXM by distance

    const int qblk = blockIdx.x;
    const int h    = blockIdx.y;
    const int b    = blockIdx.z;
    const int tid  = threadIdx.x;
    const int wave = tid >> 6;
    const int lane = tid & 63;
    const int quad = lane >> 4;
    const int t16  = lane & 15;

    // ---- bias LUT with FIXM folded in: lut[n] = bt[bucket(n)][h]*log2e - FIXM
    {
        int n = tid;
        int bucket;
        if (n < 16) {
            bucket = n;
        } else {
            int vl = (int)(__log2f((float)n * 0.0625f) * 4.0f);
            bucket = 16 + (vl < 15 ? vl : 15);
        }
        lut[n] = bt[bucket * H_ + h] * LOG2E - FIXM;
    }
    // uniform-tile shifts: arg = sa - sh, sh = FIXM - bias*log2e
    const float sh_next = FIXM - bt[h] * LOG2E;           // all-future tiles (bucket 0)
    const float sh_far  = FIXM - bt[31 * H_ + h] * LOG2E; // far-past tiles (bucket 31)

    // robust event_length read (int32 vs int64 layouts; valid lengths >= 1)
    const int len = (elen[1] == 0) ? elen[2 * b] : elen[b];
    const int ntiles = (len + BK - 1) >> 6;  // keys beyond len contribute exp()=0 exactly

    const size_t bh = ((size_t)b * H_ + h) * (size_t)(S_ * D_);
    const float* qg = qg_ + bh;
    const float* kg = kg_ + bh;
    const float* vg = vg_ + bh;
    float*       og = outg_ + bh;

    // ---- Q fragments (A-layout), scaled by (1/sqrt(64)) * log2e
    half8 qf[2];
    {
        const float qscale = 0.125f * LOG2E;
        const int row = qblk * BQ + wave * 16 + t16;
        const float* qp = qg + (size_t)row * D_ + quad * 8;
        #pragma unroll
        for (int c = 0; c < 2; ++c) {
            const float4* p = reinterpret_cast<const float4*>(qp + c * 32);
            float4 x0 = p[0], x1 = p[1];
            half8 hv;
            hv[0] = (_Float16)(x0.x * qscale); hv[1] = (_Float16)(x0.y * qscale);
            hv[2] = (_Float16)(x0.z * qscale); hv[3] = (_Float16)(x0.w * qscale);
            hv[4] = (_Float16)(x1.x * qscale); hv[5] = (_Float16)(x1.y * qscale);
            hv[6] = (_Float16)(x1.z * qscale); hv[7] = (_Float16)(x1.w * qscale);
            qf[c] = hv;
        }
    }

    floatx4 zero4 = {0.f, 0.f, 0.f, 0.f};
    floatx4 acc[4];            // O accumulator: acc[nb][r] -> row quad*4+r, dim nb*16+t16
    float l_[4];               // per-lane PARTIAL row sums (this lane's columns only)
    #pragma unroll
    for (int nb = 0; nb < 4; ++nb) acc[nb] = zero4;
    #pragma unroll
    for (int r = 0; r < 4; ++r) l_[r] = 0.f;

    const int i0 = qblk * BQ + wave * 16 + quad * 4;  // global q-row of reg r=0

    // ---- software-pipelined staging registers
    float4 kx[2][2];
    float  vx[16];
    auto prefetch = [&](int kt) {
        #pragma unroll
        for (int it = 0; it < 2; ++it) {
            int idx = tid + it * 256;
            int row = idx >> 3;
            int c8  = (idx & 7) << 3;
            const float4* p = reinterpret_cast<const float4*>(
                kg + ((size_t)(kt * BK + row) * D_ + c8));
            kx[it][0] = p[0];
            kx[it][1] = p[1];
        }
        #pragma unroll
        for (int it = 0; it < 2; ++it) {
            int key8 = kt * BK + wave * 8 + it * 32;
            #pragma unroll
            for (int jj = 0; jj < 8; ++jj)
                vx[it * 8 + jj] = vg[(size_t)(key8 + jj) * D_ + lane];
        }
    };

    prefetch(0);

    for (int kt = 0; kt < ntiles; ++kt) {
        __syncthreads();  // all waves done reading prior tile's LDS

        // ---- stage K [key][dim] and V^T [dim][key] from prefetched regs (cvt here)
        #pragma unroll
        for (int it = 0; it < 2; ++it) {
            int idx = tid + it * 256;
            int row = idx >> 3;
            int c8  = (idx & 7) << 3;
            float4 x0 = kx[it][0], x1 = kx[it][1];
            half8 hv;
            hv[0]=(_Float16)x0.x; hv[1]=(_Float16)x0.y; hv[2]=(_Float16)x0.z; hv[3]=(_Float16)x0.w;
            hv[4]=(_Float16)x1.x; hv[5]=(_Float16)x1.y; hv[6]=(_Float16)x1.z; hv[7]=(_Float16)x1.w;
            *reinterpret_cast<half8*>(&Kl[row][c8]) = hv;
        }
        #pragma unroll
        for (int it = 0; it < 2; ++it) {
            int key8 = wave * 8 + it * 32;
            half8 hv;
            #pragma unroll
            for (int jj = 0; jj < 8; ++jj) hv[jj] = (_Float16)vx[it * 8 + jj];
            *reinterpret_cast<half8*>(&Vt[lane][key8]) = hv;
        }
        __syncthreads();

        // issue next tile's global loads now; latency hides under compute below
        if (kt + 1 < ntiles) prefetch(kt + 1);

        // ---- S = (Q * log2e/8) K^T
        floatx4 sa[4];
        #pragma unroll
        for (int nb = 0; nb < 4; ++nb) sa[nb] = zero4;
        #pragma unroll
        for (int kc = 0; kc < 2; ++kc) {
            half8 a = qf[kc];
            #pragma unroll
            for (int nb = 0; nb < 4; ++nb) {
                half8 bb = *reinterpret_cast<const half8*>(
                    &Kl[nb * 16 + t16][kc * 32 + quad * 8]);
                sa[nb] = __builtin_amdgcn_mfma_f32_16x16x32_f16(a, bb, sa[nb], 0, 0, 0);
            }
        }

        // ---- bias + fixed shift (tile-uniform except within 5 tiles of diagonal)
        if (kt > qblk) {
            #pragma unroll
            for (int nb = 0; nb < 4; ++nb)
                #pragma unroll
                for (int r = 0; r < 4; ++r) sa[nb][r] -= sh_next;
        } else if (kt < qblk - 4) {
            #pragma unroll
            for (int nb = 0; nb < 4; ++nb)
                #pragma unroll
                for (int r = 0; r < 4; ++r) sa[nb][r] -= sh_far;
        } else {
            const int d0 = i0 - kt * BK - t16;
            #pragma unroll
            for (int nb = 0; nb < 4; ++nb) {
                #pragma unroll
                for (int r = 0; r < 4; ++r) {
                    int d = d0 + r - nb * 16;
                    d = d < 0 ? 0 : (d > 255 ? 255 : d);
                    sa[nb][r] += lut[d];
                }
            }
        }
        // key-padding mask: only the (block-uniform) boundary tile needs it
        if ((kt == ntiles - 1) && (len & 63)) {
            #pragma unroll
            for (int nb = 0; nb < 4; ++nb) {
                bool valid = (kt * BK + nb * 16 + t16) < len;
                #pragma unroll
                for (int r = 0; r < 4; ++r)
                    sa[nb][r] = valid ? sa[nb][r] : -1e30f;
            }
        }

        // ---- fixed-shift softmax: p = exp2(arg); no max, no rescale, no shuffles
        #pragma unroll
        for (int nb = 0; nb < 4; ++nb)
            #pragma unroll
            for (int r = 0; r < 4; ++r)
                sa[nb][r] = EXP2F(sa[nb][r]);
        #pragma unroll
        for (int r = 0; r < 4; ++r)
            l_[r] += (sa[0][r] + sa[1][r]) + (sa[2][r] + sa[3][r]);

        // ---- P: C-layout -> per-wave LDS -> A-layout (wave-local, no block barrier)
        #pragma unroll
        for (int r = 0; r < 4; ++r) {
            #pragma unroll
            for (int nb = 0; nb < 4; ++nb)
                Pl[wave][quad * 4 + r][nb * 16 + t16] = (_Float16)sa[nb][r];
        }
        asm volatile("s_waitcnt lgkmcnt(0)" ::: "memory");  // own wave's writes visible

        // ---- O += P V
        #pragma unroll
        for (int kc = 0; kc < 2; ++kc) {
            half8 a = *reinterpret_cast<const half8*>(
                &Pl[wave][t16][kc * 32 + quad * 8]);
            #pragma unroll
            for (int nb = 0; nb < 4; ++nb) {
                half8 bb = *reinterpret_cast<const half8*>(
                    &Vt[nb * 16 + t16][kc * 32 + quad * 8]);
                acc[nb] = __builtin_amdgcn_mfma_f32_16x16x32_f16(a, bb, acc[nb], 0, 0, 0);
            }
        }
    }

    // ---- epilogue: reduce l across the 16 column-lanes (once), normalize, store
    #pragma unroll
    for (int r = 0; r < 4; ++r) {
        float lv = l_[r];
        #pragma unroll
        for (int off = 1; off < 16; off <<= 1)
            lv += __shfl_xor(lv, off, 64);
        float inv = 1.f / lv;
        #pragma unroll
        for (int nb = 0; nb < 4; ++nb) {
            og[(size_t)(qblk * BQ + wave * 16 + quad * 4 + r) * D_ + nb * 16 + t16]
                = acc[nb][r] * inv;
        }
    }
}

extern "C" void kernel_launch(void* const* d_in, const int* in_sizes, int n_in,
                              void* d_out, int out_size, void* d_ws, size_t ws_size,
                              hipStream_t stream) {
    const float* q  = (const float*)d_in[0];
    const float* k  = (const float*)d_in[1];
    const float* v  = (const float*)d_in[2];
    const float* bt = (const float*)d_in[3];
    const int*   el = (const int*)d_in[4];
    float* out = (float*)d_out;
    dim3 grid(S_ / BQ, H_, B_);
    t5_attn_kernel<<<grid, 256, 0, stream>>>(q, k, v, bt, el, out);
}

// Round 4
// 122.188 us; speedup vs baseline: 1.2367x; 1.0431x over previous
//
#include <hip/hip_runtime.h>
#include <hip/hip_bf16.h>

#define B_ 2
#define H_ 16
#define S_ 2048
#define D_ 64
#define BQ 128     // q-rows per block: 4 waves x 32 rows (2 row-groups of 16)
#define BK 64
#define LDSTR 72   // stride 144B: keeps b128 rows 16B-aligned, spreads bank-quads
#define LOG2E 1.4426950408889634f
#define FIXM 10.0f // fixed softmax shift (log2 domain); cancels exactly in O = PV/l

#if __has_builtin(__builtin_amdgcn_exp2f)
#define EXP2F(x) __builtin_amdgcn_exp2f(x)
#else
#define EXP2F(x) __expf((x) * 0.6931471805599453f)
#endif

typedef _Float16 half8 __attribute__((ext_vector_type(8)));
typedef float floatx4 __attribute__((ext_vector_type(4)));

__global__ __launch_bounds__(256, 2)
void t5_attn_kernel(const float* __restrict__ qg_, const float* __restrict__ kg_,
                    const float* __restrict__ vg_, const float* __restrict__ bt,
                    const int* __restrict__ elen, float* __restrict__ outg_)
{
    __shared__ __align__(16) _Float16 Kl[BK][LDSTR];     // [key][dim]
    __shared__ __align__(16) _Float16 Vt[D_][LDSTR];     // [dim][key] (transposed)
    __shared__ __align__(16) _Float16 Pl[4][32][LDSTR];  // per-wave P tile [qrow][key]
    __shared__ float lut[256];                           // bias*log2e - FIXM by distance

    const int qblk = blockIdx.x;
    const int h    = blockIdx.y;
    const int b    = blockIdx.z;
    const int tid  = threadIdx.x;
    const int wave = tid >> 6;
    const int lane = tid & 63;
    const int quad = lane >> 4;
    const int t16  = lane & 15;

    // ---- bias LUT with FIXM folded in: lut[n] = bt[bucket(n)][h]*log2e - FIXM
    {
        int n = tid;
        int bucket;
        if (n < 16) {
            bucket = n;
        } else {
            int vl = (int)(__log2f((float)n * 0.0625f) * 4.0f);
            bucket = 16 + (vl < 15 ? vl : 15);
        }
        lut[n] = bt[bucket * H_ + h] * LOG2E - FIXM;
    }
    // uniform-tile shifts: arg = sa - sh, sh = FIXM - bias*log2e
    const float sh_next = FIXM - bt[h] * LOG2E;           // all d<=0 (bucket 0)
    const float sh_far  = FIXM - bt[31 * H_ + h] * LOG2E; // all d>=216 (bucket 31)

    // robust event_length read (int32 vs int64 layouts; valid lengths >= 1)
    const int len = (elen[1] == 0) ? elen[2 * b] : elen[b];
    const int ntiles = (len + BK - 1) >> 6;  // keys beyond len contribute exp()=0 exactly

    const size_t bh = ((size_t)b * H_ + h) * (size_t)(S_ * D_);
    const float* qg = qg_ + bh;
    const float* kg = kg_ + bh;
    const float* vg = vg_ + bh;
    float*       og = outg_ + bh;

    // ---- Q fragments: 2 row-groups x 2 k-chunks, scaled by (1/8)*log2e
    half8 qf[2][2];
    #pragma unroll
    for (int rg = 0; rg < 2; ++rg) {
        const float qscale = 0.125f * LOG2E;
        const int row = qblk * BQ + wave * 32 + rg * 16 + t16;
        const float* qp = qg + (size_t)row * D_ + quad * 8;
        #pragma unroll
        for (int c = 0; c < 2; ++c) {
            const float4* p = reinterpret_cast<const float4*>(qp + c * 32);
            float4 x0 = p[0], x1 = p[1];
            half8 hv;
            hv[0] = (_Float16)(x0.x * qscale); hv[1] = (_Float16)(x0.y * qscale);
            hv[2] = (_Float16)(x0.z * qscale); hv[3] = (_Float16)(x0.w * qscale);
            hv[4] = (_Float16)(x1.x * qscale); hv[5] = (_Float16)(x1.y * qscale);
            hv[6] = (_Float16)(x1.z * qscale); hv[7] = (_Float16)(x1.w * qscale);
            qf[rg][c] = hv;
        }
    }

    floatx4 zero4 = {0.f, 0.f, 0.f, 0.f};
    floatx4 acc[2][4];         // acc[rg][nb][r]: row rg*16+quad*4+r, dim nb*16+t16
    float l_[2][4];            // per-lane PARTIAL row sums
    #pragma unroll
    for (int rg = 0; rg < 2; ++rg) {
        #pragma unroll
        for (int nb = 0; nb < 4; ++nb) acc[rg][nb] = zero4;
        #pragma unroll
        for (int r = 0; r < 4; ++r) l_[rg][r] = 0.f;
    }

    const int i_lo = qblk * BQ + wave * 32;  // first q-row this wave owns

    // ---- software-pipelined staging registers
    float4 kx[2][2];
    float  vx[16];
    auto prefetch = [&](int kt) {
        #pragma unroll
        for (int it = 0; it < 2; ++it) {
            int idx = tid + it * 256;
            int row = idx >> 3;
            int c8  = (idx & 7) << 3;
            const float4* p = reinterpret_cast<const float4*>(
                kg + ((size_t)(kt * BK + row) * D_ + c8));
            kx[it][0] = p[0];
            kx[it][1] = p[1];
        }
        #pragma unroll
        for (int it = 0; it < 2; ++it) {
            int key8 = kt * BK + wave * 8 + it * 32;
            #pragma unroll
            for (int jj = 0; jj < 8; ++jj)
                vx[it * 8 + jj] = vg[(size_t)(key8 + jj) * D_ + lane];
        }
    };

    prefetch(0);

    for (int kt = 0; kt < ntiles; ++kt) {
        __syncthreads();  // all waves done reading prior tile's LDS

        // ---- stage K [key][dim] and V^T [dim][key] from prefetched regs
        #pragma unroll
        for (int it = 0; it < 2; ++it) {
            int idx = tid + it * 256;
            int row = idx >> 3;
            int c8  = (idx & 7) << 3;
            float4 x0 = kx[it][0], x1 = kx[it][1];
            half8 hv;
            hv[0]=(_Float16)x0.x; hv[1]=(_Float16)x0.y; hv[2]=(_Float16)x0.z; hv[3]=(_Float16)x0.w;
            hv[4]=(_Float16)x1.x; hv[5]=(_Float16)x1.y; hv[6]=(_Float16)x1.z; hv[7]=(_Float16)x1.w;
            *reinterpret_cast<half8*>(&Kl[row][c8]) = hv;
        }
        #pragma unroll
        for (int it = 0; it < 2; ++it) {
            int key8 = wave * 8 + it * 32;
            half8 hv;
            #pragma unroll
            for (int jj = 0; jj < 8; ++jj) hv[jj] = (_Float16)vx[it * 8 + jj];
            *reinterpret_cast<half8*>(&Vt[lane][key8]) = hv;
        }
        __syncthreads();

        // issue next tile's global loads; latency hides under compute below
        if (kt + 1 < ntiles) prefetch(kt + 1);

        // ---- S = (Q * log2e/8) K^T : each B-frag read feeds BOTH row-groups
        floatx4 sa[2][4];
        #pragma unroll
        for (int rg = 0; rg < 2; ++rg)
            #pragma unroll
            for (int nb = 0; nb < 4; ++nb) sa[rg][nb] = zero4;
        #pragma unroll
        for (int kc = 0; kc < 2; ++kc) {
            half8 a0 = qf[0][kc], a1 = qf[1][kc];
            #pragma unroll
            for (int nb = 0; nb < 4; ++nb) {
                half8 bb = *reinterpret_cast<const half8*>(
                    &Kl[nb * 16 + t16][kc * 32 + quad * 8]);
                sa[0][nb] = __builtin_amdgcn_mfma_f32_16x16x32_f16(a0, bb, sa[0][nb], 0, 0, 0);
                sa[1][nb] = __builtin_amdgcn_mfma_f32_16x16x32_f16(a1, bb, sa[1][nb], 0, 0, 0);
            }
        }

        // ---- bias + fixed shift (wave-uniform classification over the 32 rows)
        const int base = kt * BK;
        if (i_lo + 31 <= base) {             // all d <= 0 -> bucket 0
            #pragma unroll
            for (int rg = 0; rg < 2; ++rg)
                #pragma unroll
                for (int nb = 0; nb < 4; ++nb)
                    #pragma unroll
                    for (int r = 0; r < 4; ++r) sa[rg][nb][r] -= sh_next;
        } else if (i_lo >= base + 279) {     // all d >= 216 -> bucket 31
            #pragma unroll
            for (int rg = 0; rg < 2; ++rg)
                #pragma unroll
                for (int nb = 0; nb < 4; ++nb)
                    #pragma unroll
                    for (int r = 0; r < 4; ++r) sa[rg][nb][r] -= sh_far;
        } else {
            #pragma unroll
            for (int rg = 0; rg < 2; ++rg) {
                const int d0 = i_lo + rg * 16 + quad * 4 - base - t16;
                #pragma unroll
                for (int nb = 0; nb < 4; ++nb) {
                    #pragma unroll
                    for (int r = 0; r < 4; ++r) {
                        int d = d0 + r - nb * 16;
                        d = d < 0 ? 0 : (d > 255 ? 255 : d);
                        sa[rg][nb][r] += lut[d];
                    }
                }
            }
        }
        // key-padding mask: only the (block-uniform) boundary tile needs it
        if ((kt == ntiles - 1) && (len & 63)) {
            #pragma unroll
            for (int nb = 0; nb < 4; ++nb) {
                bool valid = (base + nb * 16 + t16) < len;
                #pragma unroll
                for (int rg = 0; rg < 2; ++rg)
                    #pragma unroll
                    for (int r = 0; r < 4; ++r)
                        sa[rg][nb][r] = valid ? sa[rg][nb][r] : -1e30f;
            }
        }

        // ---- fixed-shift softmax: p = exp2(arg); no max, no rescale, no shuffles
        #pragma unroll
        for (int rg = 0; rg < 2; ++rg) {
            #pragma unroll
            for (int nb = 0; nb < 4; ++nb)
                #pragma unroll
                for (int r = 0; r < 4; ++r)
                    sa[rg][nb][r] = EXP2F(sa[rg][nb][r]);
            #pragma unroll
            for (int r = 0; r < 4; ++r)
                l_[rg][r] += (sa[rg][0][r] + sa[rg][1][r]) + (sa[rg][2][r] + sa[rg][3][r]);
        }

        // ---- P: C-layout -> per-wave LDS -> A-layout (wave-local fence only)
        #pragma unroll
        for (int rg = 0; rg < 2; ++rg)
            #pragma unroll
            for (int r = 0; r < 4; ++r)
                #pragma unroll
                for (int nb = 0; nb < 4; ++nb)
                    Pl[wave][rg * 16 + quad * 4 + r][nb * 16 + t16] = (_Float16)sa[rg][nb][r];
        asm volatile("s_waitcnt lgkmcnt(0)" ::: "memory");  // own wave's writes visible

        // ---- O += P V : each B-frag read feeds BOTH row-groups
        #pragma unroll
        for (int kc = 0; kc < 2; ++kc) {
            half8 a0 = *reinterpret_cast<const half8*>(
                &Pl[wave][t16][kc * 32 + quad * 8]);
            half8 a1 = *reinterpret_cast<const half8*>(
                &Pl[wave][16 + t16][kc * 32 + quad * 8]);
            #pragma unroll
            for (int nb = 0; nb < 4; ++nb) {
                half8 bb = *reinterpret_cast<const half8*>(
                    &Vt[nb * 16 + t16][kc * 32 + quad * 8]);
                acc[0][nb] = __builtin_amdgcn_mfma_f32_16x16x32_f16(a0, bb, acc[0][nb], 0, 0, 0);
                acc[1][nb] = __builtin_amdgcn_mfma_f32_16x16x32_f16(a1, bb, acc[1][nb], 0, 0, 0);
            }
        }
    }

    // ---- epilogue: reduce l across the 16 column-lanes (once), normalize, store
    #pragma unroll
    for (int rg = 0; rg < 2; ++rg) {
        #pragma unroll
        for (int r = 0; r < 4; ++r) {
            float lv = l_[rg][r];
            #pragma unroll
            for (int off = 1; off < 16; off <<= 1)
                lv += __shfl_xor(lv, off, 64);
            float inv = 1.f / lv;
            const int row = qblk * BQ + wave * 32 + rg * 16 + quad * 4 + r;
            #pragma unroll
            for (int nb = 0; nb < 4; ++nb)
                og[(size_t)row * D_ + nb * 16 + t16] = acc[rg][nb][r] * inv;
        }
    }
}

extern "C" void kernel_launch(void* const* d_in, const int* in_sizes, int n_in,
                              void* d_out, int out_size, void* d_ws, size_t ws_size,
                              hipStream_t stream) {
    const float* q  = (const float*)d_in[0];
    const float* k  = (const float*)d_in[1];
    const float* v  = (const float*)d_in[2];
    const float* bt = (const float*)d_in[3];
    const int*   el = (const int*)d_in[4];
    float* out = (float*)d_out;
    dim3 grid(S_ / BQ, H_, B_);
    t5_attn_kernel<<<grid, 256, 0, stream>>>(q, k, v, bt, el, out);
}

// Round 6
// 117.557 us; speedup vs baseline: 1.2854x; 1.0394x over previous
//
#include <hip/hip_runtime.h>
#include <hip/hip_bf16.h>

#define B_ 2
#define H_ 16
#define S_ 2048
#define D_ 64
#define BQ 128     // q-rows per block: 4 waves x 32 rows (2 row-groups of 16)
#define BK 64
#define LDSTR 72   // stride 144B: keeps b128 rows 16B-aligned, spreads bank-quads
#define LOG2E 1.4426950408889634f
#define FIXM 10.0f // fixed softmax shift (log2 domain); cancels exactly in O = PV/l

#if __has_builtin(__builtin_amdgcn_exp2f)
#define EXP2F(x) __builtin_amdgcn_exp2f(x)
#else
#define EXP2F(x) __expf((x) * 0.6931471805599453f)
#endif

typedef _Float16 half8 __attribute__((ext_vector_type(8)));
typedef _Float16 half4 __attribute__((ext_vector_type(4)));
typedef __fp16   fp16x2 __attribute__((ext_vector_type(2)));  // cvt_pkrtz return type
typedef float floatx4 __attribute__((ext_vector_type(4)));

__global__ __launch_bounds__(256, 2)
void t5_attn_kernel(const float* __restrict__ qg_, const float* __restrict__ kg_,
                    const float* __restrict__ vg_, const float* __restrict__ bt,
                    const int* __restrict__ elen, float* __restrict__ outg_)
{
    // double-buffered K/V staging; per-wave P scratch; total ~56.3 KB (<64 KB)
    __shared__ __align__(16) _Float16 Kl[2][BK][LDSTR];  // [buf][key][dim]
    __shared__ __align__(16) _Float16 Vt[2][D_][LDSTR];  // [buf][dim][key]
    __shared__ __align__(16) _Float16 Pl[4][32][LDSTR];  // per-wave P [qrow][key]
    __shared__ float lut[256];                           // bias*log2e - FIXM

    const int qblk = blockIdx.x;
    const int h    = blockIdx.y;
    const int b    = blockIdx.z;
    const int tid  = threadIdx.x;
    const int wave = tid >> 6;
    const int lane = tid & 63;
    const int quad = lane >> 4;
    const int t16  = lane & 15;

    // ---- bias LUT with FIXM folded in: lut[n] = bt[bucket(n)][h]*log2e - FIXM
    {
        int n = tid;
        int bucket;
        if (n < 16) {
            bucket = n;
        } else {
            int vl = (int)(__log2f((float)n * 0.0625f) * 4.0f);
            bucket = 16 + (vl < 15 ? vl : 15);
        }
        lut[n] = bt[bucket * H_ + h] * LOG2E - FIXM;
    }
    // uniform-tile shifts: arg = sa - sh, sh = FIXM - bias*log2e
    const float sh_next = FIXM - bt[h] * LOG2E;           // all d<=0 (bucket 0)
    const float sh_far  = FIXM - bt[31 * H_ + h] * LOG2E; // all d>=216 (bucket 31)

    // robust event_length read (int32 vs int64 layouts; valid lengths >= 1)
    const int len = (elen[1] == 0) ? elen[2 * b] : elen[b];
    const int ntiles = (len + BK - 1) >> 6;  // keys beyond len give exp()=0 exactly

    const size_t bh = ((size_t)b * H_ + h) * (size_t)(S_ * D_);
    const float* qg = qg_ + bh;
    const float* kg = kg_ + bh;
    const float* vg = vg_ + bh;
    float*       og = outg_ + bh;

    // ---- Q fragments: 2 row-groups x 2 k-chunks, scaled by (1/8)*log2e.
    // Built in A-layout; used in the B slot (A/B lane-mappings coincide for
    // 16x16x32), so QK^T computes S^T = K.Q^T: C row=key, col=qrow.
    half8 qf[2][2];
    #pragma unroll
    for (int rg = 0; rg < 2; ++rg) {
        const float qscale = 0.125f * LOG2E;
        const int row = qblk * BQ + wave * 32 + rg * 16 + t16;
        const float* qp = qg + (size_t)row * D_ + quad * 8;
        #pragma unroll
        for (int c = 0; c < 2; ++c) {
            const float4* p = reinterpret_cast<const float4*>(qp + c * 32);
            float4 x0 = p[0], x1 = p[1];
            half8 hv;
            hv[0] = (_Float16)(x0.x * qscale); hv[1] = (_Float16)(x0.y * qscale);
            hv[2] = (_Float16)(x0.z * qscale); hv[3] = (_Float16)(x0.w * qscale);
            hv[4] = (_Float16)(x1.x * qscale); hv[5] = (_Float16)(x1.y * qscale);
            hv[6] = (_Float16)(x1.z * qscale); hv[7] = (_Float16)(x1.w * qscale);
            qf[rg][c] = hv;
        }
    }

    floatx4 zero4 = {0.f, 0.f, 0.f, 0.f};
    floatx4 acc[2][4];         // acc[rg][nb][r]: qrow rg*16+quad*4+r, dim nb*16+t16
    float l_[2];               // per-lane partial row-sum for qrow rg*16+t16
    #pragma unroll
    for (int rg = 0; rg < 2; ++rg) {
        #pragma unroll
        for (int nb = 0; nb < 4; ++nb) acc[rg][nb] = zero4;
        l_[rg] = 0.f;
    }

    const int i_lo = qblk * BQ + wave * 32;  // first q-row this wave owns

    // ---- software-pipelined staging registers
    float4 kx[2][2];
    float  vx[16];
    auto prefetch = [&](int kt) {
        #pragma unroll
        for (int it = 0; it < 2; ++it) {
            int idx = tid + it * 256;
            int row = idx >> 3;
            int c8  = (idx & 7) << 3;
            const float4* p = reinterpret_cast<const float4*>(
                kg + ((size_t)(kt * BK + row) * D_ + c8));
            kx[it][0] = p[0];
            kx[it][1] = p[1];
        }
        #pragma unroll
        for (int it = 0; it < 2; ++it) {
            int key8 = kt * BK + wave * 8 + it * 32;
            #pragma unroll
            for (int jj = 0; jj < 8; ++jj)
                vx[it * 8 + jj] = vg[(size_t)(key8 + jj) * D_ + lane];
        }
    };
    auto stage = [&](int buf) {
        #pragma unroll
        for (int it = 0; it < 2; ++it) {
            int idx = tid + it * 256;
            int row = idx >> 3;
            int c8  = (idx & 7) << 3;
            float4 x0 = kx[it][0], x1 = kx[it][1];
            half8 hv;
            hv[0]=(_Float16)x0.x; hv[1]=(_Float16)x0.y; hv[2]=(_Float16)x0.z; hv[3]=(_Float16)x0.w;
            hv[4]=(_Float16)x1.x; hv[5]=(_Float16)x1.y; hv[6]=(_Float16)x1.z; hv[7]=(_Float16)x1.w;
            *reinterpret_cast<half8*>(&Kl[buf][row][c8]) = hv;
        }
        #pragma unroll
        for (int it = 0; it < 2; ++it) {
            int key8 = wave * 8 + it * 32;
            half8 hv;
            #pragma unroll
            for (int jj = 0; jj < 8; ++jj) hv[jj] = (_Float16)vx[it * 8 + jj];
            *reinterpret_cast<half8*>(&Vt[buf][lane][key8]) = hv;
        }
    };

    prefetch(0);
    stage(0);
    __syncthreads();

    for (int kt = 0; kt < ntiles; ++kt) {
        const int cur = kt & 1;
        const bool more = (kt + 1) < ntiles;
        if (more) prefetch(kt + 1);  // global->regs, hides under compute below

        // ---- S^T = K (Q*log2e/8)^T : row=key (quad*4+r), col=qrow (t16)
        floatx4 sa[2][4];
        #pragma unroll
        for (int rg = 0; rg < 2; ++rg)
            #pragma unroll
            for (int nb = 0; nb < 4; ++nb) sa[rg][nb] = zero4;
        #pragma unroll
        for (int kc = 0; kc < 2; ++kc) {
            #pragma unroll
            for (int nb = 0; nb < 4; ++nb) {
                half8 af = *reinterpret_cast<const half8*>(
                    &Kl[cur][nb * 16 + t16][kc * 32 + quad * 8]);
                sa[0][nb] = __builtin_amdgcn_mfma_f32_16x16x32_f16(af, qf[0][kc], sa[0][nb], 0, 0, 0);
                sa[1][nb] = __builtin_amdgcn_mfma_f32_16x16x32_f16(af, qf[1][kc], sa[1][nb], 0, 0, 0);
            }
        }

        // ---- bias + fixed shift (wave-uniform classification over 32 rows)
        const int base = kt * BK;
        if (i_lo + 31 <= base) {             // all d <= 0 -> bucket 0
            #pragma unroll
            for (int rg = 0; rg < 2; ++rg)
                #pragma unroll
                for (int nb = 0; nb < 4; ++nb)
                    #pragma unroll
                    for (int r = 0; r < 4; ++r) sa[rg][nb][r] -= sh_next;
        } else if (i_lo >= base + 279) {     // all d >= 216 -> bucket 31
            #pragma unroll
            for (int rg = 0; rg < 2; ++rg)
                #pragma unroll
                for (int nb = 0; nb < 4; ++nb)
                    #pragma unroll
                    for (int r = 0; r < 4; ++r) sa[rg][nb][r] -= sh_far;
        } else {
            #pragma unroll
            for (int rg = 0; rg < 2; ++rg) {
                // d = qrow - key = (i_lo+rg*16+t16) - (base+nb*16+quad*4+r)
                const int d0 = i_lo + rg * 16 + t16 - base - quad * 4;
                #pragma unroll
                for (int nb = 0; nb < 4; ++nb) {
                    #pragma unroll
                    for (int r = 0; r < 4; ++r) {
                        int d = d0 - nb * 16 - r;
                        d = d < 0 ? 0 : (d > 255 ? 255 : d);
                        sa[rg][nb][r] += lut[d];
                    }
                }
            }
        }
        // key-padding mask: only the (block-uniform) boundary tile needs it
        if ((kt == ntiles - 1) && (len & 63)) {
            #pragma unroll
            for (int nb = 0; nb < 4; ++nb) {
                #pragma unroll
                for (int r = 0; r < 4; ++r) {
                    bool valid = (base + nb * 16 + quad * 4 + r) < len;
                    #pragma unroll
                    for (int rg = 0; rg < 2; ++rg)
                        sa[rg][nb][r] = valid ? sa[rg][nb][r] : -1e30f;
                }
            }
        }

        // ---- fixed-shift softmax + partial l (no max, no rescale, no shuffles)
        #pragma unroll
        for (int rg = 0; rg < 2; ++rg) {
            float s = 0.f;
            #pragma unroll
            for (int nb = 0; nb < 4; ++nb)
                #pragma unroll
                for (int r = 0; r < 4; ++r) {
                    sa[rg][nb][r] = EXP2F(sa[rg][nb][r]);
                    s += sa[rg][nb][r];
                }
            l_[rg] += s;
        }

        // ---- P: S^T C-layout is key-contiguous per lane -> packed b64 writes
        #pragma unroll
        for (int rg = 0; rg < 2; ++rg) {
            #pragma unroll
            for (int nb = 0; nb < 4; ++nb) {
                fp16x2 lo = __builtin_amdgcn_cvt_pkrtz(sa[rg][nb][0], sa[rg][nb][1]);
                fp16x2 hi = __builtin_amdgcn_cvt_pkrtz(sa[rg][nb][2], sa[rg][nb][3]);
                half4 w;
                w[0] = (_Float16)lo[0]; w[1] = (_Float16)lo[1];
                w[2] = (_Float16)hi[0]; w[3] = (_Float16)hi[1];
                *reinterpret_cast<half4*>(
                    &Pl[wave][rg * 16 + t16][nb * 16 + quad * 4]) = w;
            }
        }
        asm volatile("s_waitcnt lgkmcnt(0)" ::: "memory");  // own wave's writes visible

        // ---- O += P V
        #pragma unroll
        for (int kc = 0; kc < 2; ++kc) {
            half8 a0 = *reinterpret_cast<const half8*>(
                &Pl[wave][t16][kc * 32 + quad * 8]);
            half8 a1 = *reinterpret_cast<const half8*>(
                &Pl[wave][16 + t16][kc * 32 + quad * 8]);
            #pragma unroll
            for (int nb = 0; nb < 4; ++nb) {
                half8 bv = *reinterpret_cast<const half8*>(
                    &Vt[cur][nb * 16 + t16][kc * 32 + quad * 8]);
                acc[0][nb] = __builtin_amdgcn_mfma_f32_16x16x32_f16(a0, bv, acc[0][nb], 0, 0, 0);
                acc[1][nb] = __builtin_amdgcn_mfma_f32_16x16x32_f16(a1, bv, acc[1][nb], 0, 0, 0);
            }
        }

        // ---- stage next tile into the other buffer; one barrier per iteration
        if (more) stage(cur ^ 1);
        __syncthreads();
    }

    // ---- epilogue: reduce l across quads (lane bits 4,5), normalize, store
    #pragma unroll
    for (int rg = 0; rg < 2; ++rg) {
        float lv = l_[rg];
        lv += __shfl_xor(lv, 16, 64);
        lv += __shfl_xor(lv, 32, 64);
        float inv = 1.f / lv;  // l for qrow rg*16+t16, replicated across quads
        #pragma unroll
        for (int r = 0; r < 4; ++r) {
            int rowloc = quad * 4 + r;  // local row this lane's acc holds
            float invr = __shfl(inv, (lane & 48) | rowloc, 64);  // lane with t16=rowloc
            const int row = qblk * BQ + wave * 32 + rg * 16 + rowloc;
            #pragma unroll
            for (int nb = 0; nb < 4; ++nb)
                og[(size_t)row * D_ + nb * 16 + t16] = acc[rg][nb][r] * invr;
        }
    }
}

extern "C" void kernel_launch(void* const* d_in, const int* in_sizes, int n_in,
                              void* d_out, int out_size, void* d_ws, size_t ws_size,
                              hipStream_t stream) {
    const float* q  = (const float*)d_in[0];
    const float* k  = (const float*)d_in[1];
    const float* v  = (const float*)d_in[2];
    const float* bt = (const float*)d_in[3];
    const int*   el = (const int*)d_in[4];
    float* out = (float*)d_out;
    dim3 grid(S_ / BQ, H_, B_);
    t5_attn_kernel<<<grid, 256, 0, stream>>>(q, k, v, bt, el, out);
}